// Round 7
// baseline (4419.911 us; speedup 1.0000x reference)
//
#include <hip/hip_runtime.h>

typedef __attribute__((ext_vector_type(8))) short short8;
typedef __attribute__((ext_vector_type(4))) float f32x4;
typedef unsigned long long ull;

#define D_DIM 1024
#define H_DIM 1024
#define FH 4096
#define NB 64
#define TT 512
#define MROWS (NB * TT)   // 32768
#define SCAN_BLOCKS 256

__device__ __forceinline__ ushort f2bf(float f) {
  union { float f; unsigned u; } v; v.f = f;
  unsigned u = v.u;
  return (ushort)((u + 0x7FFFu + ((u >> 16) & 1u)) >> 16);
}
__device__ __forceinline__ float bf2f(ushort h) {
  union { unsigned u; float f; } v; v.u = ((unsigned)h) << 16;
  return v.f;
}

// ---------------------------------------------------------------------------
// Transpose + fp32->bf16 convert + gate-interleaved column permutation.
// W: [1024][4096] row-major.  WT row r = b*32 + hc_local*4 + gate  maps to
// original column  oc = gate*1024 + b*8 + hc_local.  WT: [4096][1024] bf16.
// ---------------------------------------------------------------------------
__global__ void transpose_perm(const float* __restrict__ W, ushort* __restrict__ WT) {
  __shared__ ushort tile[64][65];
  int ocTile = blockIdx.x * 64;
  int kTile  = blockIdx.y * 64;
  int tx = threadIdx.x & 63, ty = threadIdx.x >> 6;
  #pragma unroll
  for (int i = 0; i < 16; ++i) {
    int r = ty + i * 4;  // k offset
    float v = W[(size_t)(kTile + r) * FH + ocTile + tx];
    tile[r][tx] = f2bf(v);
  }
  __syncthreads();
  #pragma unroll
  for (int i = 0; i < 16; ++i) {
    int c = ty + i * 4;              // column offset within tile
    int oc = ocTile + c;
    int gate = oc >> 10, rem = oc & 1023;
    int b = rem >> 3, hcl = rem & 7;
    int r_out = b * 32 + hcl * 4 + gate;
    WT[(size_t)r_out * D_DIM + kTile + tx] = tile[tx][c];
  }
}

// x fp32 -> bf16, one float4 per thread. grid 32768, block 256.
__global__ void cvt_x(const float* __restrict__ x, ushort* __restrict__ xb) {
  size_t i = (size_t)blockIdx.x * blockDim.x + threadIdx.x;
  const float4* x4 = (const float4*)x;
  float4 v = x4[i];
  ushort4 o; o.x = f2bf(v.x); o.y = f2bf(v.y); o.z = f2bf(v.z); o.w = f2bf(v.w);
  ((ushort4*)xb)[i] = o;
}

// h0 fp32 -> packed tagged ull buffer: hP[row*512+p] = (1<<32)|(bf16 pair).
// grid 128, block 256.
__global__ void cvt_h0_packed(const float* __restrict__ h0, ull* __restrict__ hP) {
  int i = blockIdx.x * blockDim.x + threadIdx.x;   // 0..32767
  int row = i >> 9, p = i & 511;
  float a = h0[row * 1024 + p * 2];
  float b = h0[row * 1024 + p * 2 + 1];
  unsigned hbits = (unsigned)f2bf(a) | ((unsigned)f2bf(b) << 16);
  hP[i] = (((ull)1) << 32) | (ull)hbits;
}

// zero the tag buffer for the second ping-pong half (every launch: graph
// replays would otherwise leave tag-513 garbage that aliases fresh tags).
// grid 128, block 256.
__global__ void zero_h1(ull* __restrict__ p) {
  p[blockIdx.x * blockDim.x + threadIdx.x] = 0ull;
}

// ---------------------------------------------------------------------------
// xz GEMM: A = x_bf16 [32768][1024], B = WxT_perm [4096][1024] (both K-contig)
// 128x128 tile, BK=64, 256 threads (4 waves as 2x2 of 64x64).
// ---------------------------------------------------------------------------
__global__ __launch_bounds__(256) void gemm_xz(const ushort* __restrict__ A,
                                               const ushort* __restrict__ B,
                                               ushort* __restrict__ xz) {
  __shared__ ushort As[128][72];
  __shared__ ushort Bs[128][72];
  int bid = blockIdx.x;
  int nb = bid & 31, mb = bid >> 5;
  int m0 = mb * 128, n0 = nb * 128;
  int tid = threadIdx.x;
  int lane = tid & 63, w = tid >> 6;
  int wm = w >> 1, wn = w & 1;
  int quad = lane >> 4, l15 = lane & 15;

  f32x4 acc[4][4];
  #pragma unroll
  for (int i = 0; i < 4; ++i)
    #pragma unroll
    for (int j = 0; j < 4; ++j) acc[i][j] = (f32x4)0.f;

  for (int k0 = 0; k0 < D_DIM; k0 += 64) {
    #pragma unroll
    for (int q = 0; q < 4; ++q) {
      int seg = q * 256 + tid;          // 0..1023
      int row = seg >> 3, k8 = seg & 7;
      uint4 va = *(const uint4*)(A + (size_t)(m0 + row) * D_DIM + k0 + k8 * 8);
      *(uint4*)(&As[row][k8 * 8]) = va;
      uint4 vb = *(const uint4*)(B + (size_t)(n0 + row) * D_DIM + k0 + k8 * 8);
      *(uint4*)(&Bs[row][k8 * 8]) = vb;
    }
    __syncthreads();
    #pragma unroll
    for (int kc = 0; kc < 2; ++kc) {
      int krow = kc * 32 + quad * 8;
      short8 a[4], b[4];
      #pragma unroll
      for (int mt = 0; mt < 4; ++mt)
        a[mt] = *(const short8*)(&As[wm * 64 + mt * 16 + l15][krow]);
      #pragma unroll
      for (int nt = 0; nt < 4; ++nt)
        b[nt] = *(const short8*)(&Bs[wn * 64 + nt * 16 + l15][krow]);
      #pragma unroll
      for (int mt = 0; mt < 4; ++mt)
        #pragma unroll
        for (int nt = 0; nt < 4; ++nt)
          acc[mt][nt] = __builtin_amdgcn_mfma_f32_16x16x32_bf16(a[mt], b[nt], acc[mt][nt], 0, 0, 0);
    }
    __syncthreads();
  }
  // epilogue: write bf16 into [t][n][4096]
  #pragma unroll
  for (int mt = 0; mt < 4; ++mt)
    #pragma unroll
    for (int nt = 0; nt < 4; ++nt)
      #pragma unroll
      for (int r = 0; r < 4; ++r) {
        int m = m0 + wm * 64 + mt * 16 + quad * 4 + r;
        int n = n0 + wn * 64 + nt * 16 + l15;
        int t = m & 511, nn = m >> 9;
        xz[(size_t)(t * 64 + nn) * FH + n] = f2bf(acc[mt][nt][r]);
      }
}

// ---------------------------------------------------------------------------
// Persistent cooperative LSTM scan — TAGGED-WORD dataflow sync.
// 256 blocks = 4 row-groups (mg, 16 batch rows) x 64 col-groups (cg, 16
// h-cols). 4 waves; wave w owns K-slice [w*256,(w+1)*256).
//
// h is exchanged as 64-bit atomic words: (tag<<32) | (bf16 pair), where
// tag = s+1 for h_state(s). Tag and payload travel in ONE 8B atomic =>
// no vmcnt drain, no publish barrier, no flag store, no flag-poll trip.
// Consumer bursts its 32 words and retries until all tags >= t+1 (the
// h_state(t) it needs). Single L3 round trip per step in steady state.
//
// Anti-overwrite safety (2 ping-pong buffers): block X at step t writes
// h_state(t+1) over h_state(t-1). X passed its retry => X observed tag-(t+1)
// words from ALL 64 same-mg blocks; each such store is __syncthreads-ordered
// after that block's step-(t-1) loads RETURNED => nobody is still reading
// h_state(t-1). Stale-accept impossible: a reader expecting tag k can only
// see k or older until it has itself published k (same induction).
//
// Wh slice (64 cols x 1024 K = 128 KiB) staged in LDS once, XOR-swizzled
// (byte ^= (row&7)<<4): per-(nt,kc) column-slice ds_read_b128 conflict-free.
// ---------------------------------------------------------------------------
__global__ __launch_bounds__(256, 1) void lstm_scan(
    const ushort* __restrict__ xz,    // [512][64][4096] bf16 (permuted cols)
    const ushort* __restrict__ WhT,   // [4096][1024] bf16 (permuted rows)
    const float*  __restrict__ bias,  // [4096] original order
    ull* h0P, ull* h1P,               // [64][512] tagged h-pair ping-pong
    float* __restrict__ out)          // [64][512][1024] fp32
{
  __shared__ ushort whlds[64 * 1024];       // 128 KiB, XOR-swizzled rows
  __shared__ float zpart[4 * 16 * 68];      // [w][m 0..15][col 0..63], stride 68

  const int blk = blockIdx.x;     // 0..255
  const int tid = threadIdx.x;
  const int w = tid >> 6;         // wave = K-slice 0..3
  const int lane = tid & 63;
  const int quad = lane >> 4;
  const int l15 = lane & 15;

  const int mg = blk >> 6;        // 0..3   batch-row group (16 rows)
  const int cg = blk & 63;        // 0..63  col group (64 permuted cols)
  const int m0 = mg * 16;

  // ---- stage Wh slice into LDS once (XOR-swizzled 16B granules) ----
  {
    const ushort* src = WhT + (size_t)(cg * 64) * D_DIM;
    #pragma unroll
    for (int it = 0; it < 32; ++it) {
      int idx = it * 256 + tid;           // 0..8191 chunks of 16B
      int row = idx >> 7;                 // 0..63 (col index)
      int slot = idx & 127;               // 16B slot within the 2048B row
      uint4 v = *(const uint4*)(src + (size_t)row * D_DIM + slot * 8);
      int byteoff = row * 2048 + ((slot * 16) ^ ((row & 7) << 4));
      *(uint4*)((char*)whlds + byteoff) = v;
    }
  }

  // gate-phase assignment (threads 0..127): row gm 0..15, col-octet gq 0..7
  const int gm = tid >> 3;        // valid for tid < 128
  const int gq = tid & 7;
  const int hc2 = (gq >> 2) * 8 + (gq & 3) * 2;   // local h-col pair base
  const int gp = cg * 8 + (gq >> 2) * 4 + (gq & 3); // global h-pair index
  float bb[8];
  #pragma unroll
  for (int j = 0; j < 8; ++j)
    bb[j] = bias[(j & 3) * 1024 + cg * 16 + hc2 + (j >> 2)];
  float cst[2] = {0.f, 0.f};

  ull* bufs[2] = {h0P, h1P};
  __syncthreads();   // whlds ready

  for (int t = 0; t < TT; ++t) {
    const ull* rbP = bufs[t & 1];
    ull* wbP = bufs[(t + 1) & 1];
    const unsigned need = (unsigned)(t + 1);   // tag of h_state(t)

    // prefetch xz for this thread's gate-phase cols (in flight during poll)
    uint4 xzv;
    if (tid < 128)
      xzv = *(const uint4*)(xz + (size_t)(t * 64 + m0 + gm) * FH + cg * 64 + gq * 8);

    // ---- tagged burst: 32 x 8B words = h k-slice + freshness in one trip ----
    // lane reads row m0+l15, pairs pb..pb+3 per kc, pb = w*128+kc*16+quad*4
    ull areg[8][4];
    const ull* hp = rbP + (size_t)(m0 + l15) * 512 + w * 128 + quad * 4;
    for (;;) {
      #pragma unroll
      for (int kc = 0; kc < 8; ++kc)
        #pragma unroll
        for (int q2 = 0; q2 < 4; ++q2)
          areg[kc][q2] = __hip_atomic_load(hp + kc * 16 + q2,
                                           __ATOMIC_RELAXED, __HIP_MEMORY_SCOPE_AGENT);
      unsigned bad = 0;
      #pragma unroll
      for (int kc = 0; kc < 8; ++kc)
        #pragma unroll
        for (int q2 = 0; q2 < 4; ++q2)
          bad |= (unsigned)((unsigned)(areg[kc][q2] >> 32) < need);
      if (!__any((int)bad)) break;
    }

    f32x4 acc[4];
    #pragma unroll
    for (int nt = 0; nt < 4; ++nt) acc[nt] = (f32x4)0.f;

    #pragma unroll
    for (int kc = 0; kc < 8; ++kc) {
      union { unsigned d[4]; short8 s; } av;
      #pragma unroll
      for (int q2 = 0; q2 < 4; ++q2) av.d[q2] = (unsigned)areg[kc][q2];
      const int koff = (w * 512 + kc * 64 + quad * 16) ^ ((l15 & 7) << 4);
      #pragma unroll
      for (int nt = 0; nt < 4; ++nt) {
        short8 bf = *(const short8*)((const char*)whlds + (nt * 16 + l15) * 2048 + koff);
        acc[nt] = __builtin_amdgcn_mfma_f32_16x16x32_bf16(av.s, bf, acc[nt], 0, 0, 0);
      }
    }

    // write K-partials to LDS: zpart[w][m][col], stride 68 -> 2-way (free)
    #pragma unroll
    for (int nt = 0; nt < 4; ++nt)
      #pragma unroll
      for (int r = 0; r < 4; ++r) {
        int m = quad * 4 + r;
        zpart[(w * 16 + m) * 68 + nt * 16 + l15] = acc[nt][r];
      }
    __syncthreads();

    // gate phase on threads 0..127: 8 cols = 2 h-cols x 4 gates
    if (tid < 128) {
      float z[8];
      const ushort* xp = (const ushort*)&xzv;
      #pragma unroll
      for (int j = 0; j < 8; ++j) z[j] = bb[j] + bf2f(xp[j]);
      #pragma unroll
      for (int wv = 0; wv < 4; ++wv) {
        const float4* pp = (const float4*)&zpart[(wv * 16 + gm) * 68 + gq * 8];
        float4 p0 = pp[0], p1 = pp[1];
        z[0] += p0.x; z[1] += p0.y; z[2] += p0.z; z[3] += p0.w;
        z[4] += p1.x; z[5] += p1.y; z[6] += p1.z; z[7] += p1.w;
      }
      ushort hpack[2];
      float hout[2];
      #pragma unroll
      for (int p = 0; p < 2; ++p) {
        float ai = z[p * 4 + 0], af = z[p * 4 + 1], ao = z[p * 4 + 2], ag = z[p * 4 + 3];
        float ig = 1.f / (1.f + __expf(-ai));
        float fg = 1.f / (1.f + __expf(-af));
        float og = 1.f / (1.f + __expf(-ao));
        float gg = 2.f / (1.f + __expf(-2.f * ag)) - 1.f;   // tanh
        float c = fg * cst[p] + ig * gg;
        cst[p] = c;
        float th = 2.f / (1.f + __expf(-2.f * c)) - 1.f;    // tanh
        float h = og * th;
        hout[p] = h; hpack[p] = f2bf(h);
      }
      // h recurrence store: ONE tagged 8B atomic = data + publish in one trip
      unsigned hbits = (unsigned)hpack[0] | ((unsigned)hpack[1] << 16);
      ull word = (((ull)(t + 2)) << 32) | (ull)hbits;   // tag of h_state(t+1)
      __hip_atomic_store(&wbP[(size_t)(m0 + gm) * 512 + gp], word,
                         __ATOMIC_RELAXED, __HIP_MEMORY_SCOPE_AGENT);
      // output store: plain HBM, off the critical path (nothing drains it)
      float2 ho; ho.x = hout[0]; ho.y = hout[1];
      *(float2*)(out + ((size_t)(m0 + gm) * TT + t) * H_DIM + cg * 16 + hc2) = ho;
    }

    __syncthreads();   // zpart free for next step's partial writes
  }
}

// ---------------------------------------------------------------------------
extern "C" void kernel_launch(void* const* d_in, const int* in_sizes, int n_in,
                              void* d_out, int out_size, void* d_ws, size_t ws_size,
                              hipStream_t stream) {
  const float* x  = (const float*)d_in[0];   // 64*512*1024
  const float* h0 = (const float*)d_in[1];   // 64*1024
  const float* Wx = (const float*)d_in[2];   // 1024*4096
  const float* Wh = (const float*)d_in[3];   // 1024*4096
  const float* b  = (const float*)d_in[4];   // 4096
  float* out = (float*)d_out;

  char* ws = (char*)d_ws;
  ushort* xz    = (ushort*)(ws + 0);                    // 268,435,456 B
  ushort* xb    = (ushort*)(ws + 268435456);            //  67,108,864 B (dead after gemm_xz)
  ushort* WxT   = (ushort*)(ws + 335544320);            //   8,388,608 B
  ushort* WhT   = (ushort*)(ws + 343932928);            //   8,388,608 B
  // packed tagged h buffers alias the dead xb region (written AFTER gemm_xz)
  ull* h0P = (ull*)(ws + 268435456);                    // 262,144 B
  ull* h1P = (ull*)(ws + 268435456 + 262144);           // 262,144 B

  transpose_perm<<<dim3(64, 16), 256, 0, stream>>>(Wx, WxT);
  transpose_perm<<<dim3(64, 16), 256, 0, stream>>>(Wh, WhT);
  cvt_x<<<32768, 256, 0, stream>>>(x, xb);
  gemm_xz<<<8192, 256, 0, stream>>>(xb, WxT, xz);
  // xb is dead from here; stage the tagged h state into its space
  cvt_h0_packed<<<128, 256, 0, stream>>>(h0, h0P);
  zero_h1<<<128, 256, 0, stream>>>(h1P);

  void* args[] = {(void*)&xz, (void*)&WhT, (void*)&b, (void*)&h0P, (void*)&h1P,
                  (void*)&out};
  hipLaunchCooperativeKernel((const void*)lstm_scan, dim3(SCAN_BLOCKS), dim3(256), args, 0, stream);
}